// Round 1
// baseline (500.159 us; speedup 1.0000x reference)
//
#include <hip/hip_runtime.h>

// TranslateCube: out[n, y, x] = bilinear sample of img[n] at (y - dy[n], x - dx[n]),
// zero fill outside. B*T = 1024 images, H = W = 256, fp32.
//
// Mapping: one block = one image row (256 threads), grid = (B*T)*H blocks.
//   blockIdx.x >> 8  -> image index n   (H == 256 rows per image)
//   blockIdx.x & 255 -> row y
//   threadIdx.x      -> col x
// dx[n]/dy[n] are wave-uniform (index derived from blockIdx only) -> scalar loads.

constexpr int HH = 256;
constexpr int WW = 256;

__global__ __launch_bounds__(256) void translate_kernel(
    const float* __restrict__ img,
    const float* __restrict__ dx,
    const float* __restrict__ dy,
    float* __restrict__ out)
{
    const int n = blockIdx.x >> 8;    // image index
    const int y = blockIdx.x & 255;   // row
    const int x = threadIdx.x;        // col

    const float tx = dx[n];
    const float ty = dy[n];

    // Per-pixel, matching the reference arithmetic exactly:
    const float ysf = (float)y - ty;
    const float xsf = (float)x - tx;
    const float y0f = floorf(ysf);
    const float x0f = floorf(xsf);
    const float wy  = ysf - y0f;
    const float wx  = xsf - x0f;
    const int y0 = (int)y0f;
    const int x0 = (int)x0f;
    const int y1 = y0 + 1;
    const int x1 = x0 + 1;

    const bool vy0 = (y0 >= 0) && (y0 < HH);
    const bool vy1 = (y1 >= 0) && (y1 < HH);
    const bool vx0 = (x0 >= 0) && (x0 < WW);
    const bool vx1 = (x1 >= 0) && (x1 < WW);

    // Clamp for safe addressing; zero-select via validity (branchless).
    const int yc0 = min(max(y0, 0), HH - 1);
    const int yc1 = min(max(y1, 0), HH - 1);
    const int xc0 = min(max(x0, 0), WW - 1);
    const int xc1 = min(max(x1, 0), WW - 1);

    const float* base = img + (size_t)n * (HH * WW);
    const float* row0 = base + yc0 * WW;
    const float* row1 = base + yc1 * WW;

    const float c00 = (vy0 && vx0) ? row0[xc0] : 0.0f;
    const float c01 = (vy0 && vx1) ? row0[xc1] : 0.0f;
    const float c10 = (vy1 && vx0) ? row1[xc0] : 0.0f;
    const float c11 = (vy1 && vx1) ? row1[xc1] : 0.0f;

    const float top = (1.0f - wx) * c00 + wx * c01;
    const float bot = (1.0f - wx) * c10 + wx * c11;
    const float r   = (1.0f - wy) * top + wy * bot;

    out[((size_t)n * HH + y) * WW + x] = r;
}

extern "C" void kernel_launch(void* const* d_in, const int* in_sizes, int n_in,
                              void* d_out, int out_size, void* d_ws, size_t ws_size,
                              hipStream_t stream) {
    const float* img = (const float*)d_in[0];  // [B,T,H,W] fp32
    const float* dx  = (const float*)d_in[1];  // [B,T]
    const float* dy  = (const float*)d_in[2];  // [B,T]
    // d_in[3] = winsize (unused)
    float* out = (float*)d_out;

    const int BT = in_sizes[1];                // number of images (B*T)
    const int nblocks = BT * HH;               // one block per image row

    translate_kernel<<<nblocks, WW, 0, stream>>>(img, dx, dy, out);
}